// Round 7
// baseline (293.836 us; speedup 1.0000x reference)
//
#include <hip/hip_runtime.h>
#include <hip/hip_bf16.h>
#include <stdint.h>

// LightningIndexer: importance[b,q,k] = sum_h w[b,q,h] * relu( qh[b,q,:] . kv[b,k,:] )
// B=2, T=4096, C=2048, H=16, D=32.
// Pipeline: (1) cast x + pack W -> bf16, (2) MFMA GEMM projections (32x128 tiles,
// BK=64, 1280 blocks = 5/CU), (3) fused score kernel. Intermediates are HEAD-MAJOR
// (qh[16][8192][32], kh[8192][32]) so scores' fragment loads are direct,
// perfectly-coalesced 1KiB-per-wave global reads (no LDS staging needed).

typedef __attribute__((ext_vector_type(8))) short bf16x8;
typedef __attribute__((ext_vector_type(4))) float f32x4;
typedef __attribute__((ext_vector_type(2))) __fp16 f16x2;   // clang builtin half2 type

__device__ __forceinline__ unsigned short f2bf(float f) {
  union { float f; unsigned u; } c; c.f = f;
  unsigned u = c.u;
  u += 0x7FFFu + ((u >> 16) & 1u);   // round-to-nearest-even
  return (unsigned short)(u >> 16);
}

__device__ __forceinline__ f16x2 u32_to_h2(unsigned u) {
  union { unsigned u; f16x2 h; } c; c.u = u; return c.h;
}
__device__ __forceinline__ unsigned h2_to_u32(f16x2 h) {
  union { unsigned u; f16x2 h; } c; c.h = h; return c.u;
}

__device__ __forceinline__ void async_copy16(void* lds, const void* g) {
  __builtin_amdgcn_global_load_lds(
      (const __attribute__((address_space(1))) unsigned*)g,
      (__attribute__((address_space(3))) unsigned*)lds, 16, 0, 0);
}

// ---------------- kernel 1: cast x to bf16, pack Wq/Wk/Ww (+zero pad) ----------------
__global__ __launch_bounds__(256) void pack_kernel(
    const float* __restrict__ x, const float* __restrict__ Wq,
    const float* __restrict__ Wk, const float* __restrict__ Ww,
    unsigned short* __restrict__ xb, unsigned short* __restrict__ Wp) {
  const int64_t NX4 = 16777216 / 4;          // x float4 count
  int64_t i = (int64_t)blockIdx.x * 256 + threadIdx.x;
  if (i < NX4) {
    float4 v = ((const float4*)x)[i];
    ushort4 o;
    o.x = f2bf(v.x); o.y = f2bf(v.y); o.z = f2bf(v.z); o.w = f2bf(v.w);
    ((ushort4*)xb)[i] = o;
  } else {
    int p = (int)(i - NX4);                  // 0 .. 640*2048/4-1 = 327679
    int row = p >> 9;                        // 512 float4 per 2048-col row
    int col = (p & 511) << 2;
    float4 v = make_float4(0.f, 0.f, 0.f, 0.f);
    if (row < 512)      v = *(const float4*)(Wq + (int64_t)row * 2048 + col);
    else if (row < 544) v = *(const float4*)(Wk + (int64_t)(row - 512) * 2048 + col);
    else if (row < 560) v = *(const float4*)(Ww + (int64_t)(row - 544) * 2048 + col);
    ushort4 o;
    o.x = f2bf(v.x); o.y = f2bf(v.y); o.z = f2bf(v.z); o.w = f2bf(v.w);
    ((ushort4*)Wp)[p] = o;
  }
}

// ---------------- kernel 2: projections, 32x128 (m x n) tiles, BK=64, 1280 blocks ----------------
// grid (5, 256): n-tile 128 (640 cols), m-tile 32 (8192 rows). 256 threads,
// waves 1x4 in n: each wave computes 32x32. Single-buffer LDS, 2 barriers/k-step,
// 32 k-steps (same sync structure as the verified round-6 kernel; only tile
// constants changed: more blocks for TLP, half the barrier/drain count).
__global__ __launch_bounds__(256) void gemm_proj(
    const unsigned short* __restrict__ xb, const unsigned short* __restrict__ Wp,
    unsigned short* __restrict__ qh, unsigned short* __restrict__ kh,
    float* __restrict__ wf) {
  __shared__ short lds_a[32 * 64];           // 4 KB  (32 rows x 64 k)
  __shared__ short lds_b[128 * 64];          // 16 KB (128 rows x 64 k)
  const int tid = threadIdx.x;
  const int lane = tid & 63;
  const int l15 = lane & 15, quad = lane >> 4;
  const int wave = tid >> 6;
  const int wn = wave;                       // 0..3
  const int m0 = blockIdx.y * 32, n0 = blockIdx.x * 128;

  // A: 32x64 = 256 chunks (1/thread); B: 128x64 = 1024 chunks (4/thread)
  const unsigned short* ga = xb + (int64_t)(m0 + (tid >> 3)) * 2048 + (tid & 7) * 8;

  f32x4 acc[2][2] = {};

  for (int kt = 0; kt < 32; ++kt) {
    const int ko = kt * 64;
    async_copy16(&lds_a[tid * 8], ga + ko);
#pragma unroll
    for (int cc = 0; cc < 4; ++cc) {
      int c = tid + cc * 256;                // 0..1023
      int row = c >> 3, slot = c & 7;
      async_copy16(&lds_b[c * 8], Wp + (int64_t)(n0 + row) * 2048 + ko + slot * 8);
    }
    __syncthreads();
    bf16x8 af[2][2], bfr[2][2];
#pragma unroll
    for (int i = 0; i < 2; ++i)
#pragma unroll
      for (int s = 0; s < 2; ++s)
        af[i][s] = *(const bf16x8*)&lds_a[(i * 16 + l15) * 64 + s * 32 + quad * 8];
#pragma unroll
    for (int j = 0; j < 2; ++j)
#pragma unroll
      for (int s = 0; s < 2; ++s)
        bfr[j][s] = *(const bf16x8*)&lds_b[(wn * 32 + j * 16 + l15) * 64 + s * 32 + quad * 8];
#pragma unroll
    for (int s = 0; s < 2; ++s)
#pragma unroll
      for (int i = 0; i < 2; ++i)
#pragma unroll
        for (int j = 0; j < 2; ++j)
          acc[i][j] = __builtin_amdgcn_mfma_f32_16x16x32_bf16(af[i][s], bfr[j][s], acc[i][j], 0, 0, 0);
    __syncthreads();
  }

#pragma unroll
  for (int i = 0; i < 2; ++i)
#pragma unroll
    for (int j = 0; j < 2; ++j)
#pragma unroll
      for (int r = 0; r < 4; ++r) {
        int m = m0 + i * 16 + quad * 4 + r;
        int n = n0 + wn * 32 + j * 16 + l15;
        float v = acc[i][j][r];
        if (n < 512)      qh[((int64_t)(n >> 5) * 8192 + m) * 32 + (n & 31)] = f2bf(v);
        else if (n < 544) kh[(int64_t)m * 32 + (n - 512)] = f2bf(v);
        else if (n < 560) wf[m * 16 + (n - 544)] = v;   // w kept fp32
      }
}

// ---------------- kernel 3: fused scores ----------------
// Block: 128 k x 128 q tile (verified round-6 structure, unchanged). Fragment
// loads go directly to head-major qh/kh: within a wave, (l15, quad) lanes cover
// one contiguous 1 KiB block -> perfectly coalesced.
// Epilogue: cvt_pkrtz + pk_max + fdot2 = 1.5 VALU ops per element-head.
__global__ __launch_bounds__(256) void scores_kernel(
    const unsigned short* __restrict__ qh, const unsigned short* __restrict__ kh,
    const float* __restrict__ wf, float* __restrict__ out) {
  const int kt = blockIdx.x, qt = blockIdx.y, b = blockIdx.z;
  const int tid = threadIdx.x;
  const int lane = tid & 63;
  const int l15 = lane & 15, quad = lane >> 4;
  const int wave = tid >> 6;
  const int wk = wave & 1, wq = wave >> 1;

  __shared__ unsigned w2[8][132];            // packed half2 {w[q,2hp], w[q,2hp+1]}

  const int qrow0 = b * 4096 + qt * 128;
  const int krow0 = b * 4096 + kt * 128;

  // stage w tile: 128 rows x 16 heads fp32 -> half2 pairs (contiguous reads)
  {
    const float4* ws = (const float4*)(wf + (int64_t)qrow0 * 16);
#pragma unroll
    for (int r = 0; r < 2; ++r) {
      int f = tid * 2 + r;                   // 0..511 float4s
      float4 v = ws[f];
      int row = f >> 2, hb = (f & 3) * 4;    // heads hb..hb+3
      f16x2 p01, p23;
      p01.x = (__fp16)v.x; p01.y = (__fp16)v.y;
      p23.x = (__fp16)v.z; p23.y = (__fp16)v.w;
      w2[(hb >> 1) + 0][row] = h2_to_u32(p01);
      w2[(hb >> 1) + 1][row] = h2_to_u32(p23);
    }
  }

  // K fragments: shared across all heads, registers for whole kernel.
  bf16x8 ka[4];
#pragma unroll
  for (int i = 0; i < 4; ++i) {
    int kk = krow0 + wk * 64 + i * 16 + l15;
    ka[i] = *(const bf16x8*)&kh[(int64_t)kk * 32 + quad * 8];
  }

  // q base for this thread: head h, row offset j*16 -> + h*8192*32 + j*512
  const unsigned short* qbase =
      qh + (int64_t)(qrow0 + wq * 64 + l15) * 32 + quad * 8;

  f32x4 acc[4][4] = {};
  __syncthreads();

  const f16x2 hz = u32_to_h2(0u);
  const f32x4 z = {0.f, 0.f, 0.f, 0.f};

#pragma unroll
  for (int hp = 0; hp < 8; ++hp) {
    // loop-local q fragments (static indices only — no cross-iteration arrays)
    bf16x8 q0[4], q1[4];
#pragma unroll
    for (int j = 0; j < 4; ++j) {
      q0[j] = *(const bf16x8*)&qbase[(int64_t)(2 * hp) * 262144 + j * 512];
      q1[j] = *(const bf16x8*)&qbase[(int64_t)(2 * hp + 1) * 262144 + j * 512];
    }
    f16x2 wv[4];
#pragma unroll
    for (int j = 0; j < 4; ++j)
      wv[j] = u32_to_h2(w2[hp][wq * 64 + j * 16 + l15]);

#pragma unroll
    for (int i = 0; i < 4; ++i)
#pragma unroll
      for (int j = 0; j < 4; ++j) {
        f32x4 t0 = __builtin_amdgcn_mfma_f32_16x16x32_bf16(ka[i], q0[j], z, 0, 0, 0);
        f32x4 t1 = __builtin_amdgcn_mfma_f32_16x16x32_bf16(ka[i], q1[j], z, 0, 0, 0);
#pragma unroll
        for (int r = 0; r < 4; ++r) {
          f16x2 p = __builtin_amdgcn_cvt_pkrtz(t0[r], t1[r]);   // {s_h0, s_h1} f16
          p = __builtin_elementwise_max(p, hz);                  // relu both halves
          acc[i][j][r] = __builtin_amdgcn_fdot2(p, wv[j], acc[i][j][r], false);
        }
      }
  }

  // store: per (i,j) one dwordx4 along k
#pragma unroll
  for (int i = 0; i < 4; ++i)
#pragma unroll
    for (int j = 0; j < 4; ++j) {
      int q = qt * 128 + wq * 64 + j * 16 + l15;
      int k = kt * 128 + wk * 64 + i * 16 + quad * 4;
      float4 v = make_float4(acc[i][j][0], acc[i][j][1], acc[i][j][2], acc[i][j][3]);
      *(float4*)&out[((int64_t)b * 4096 + q) * 4096 + k] = v;
    }
}

extern "C" void kernel_launch(void* const* d_in, const int* in_sizes, int n_in,
                              void* d_out, int out_size, void* d_ws, size_t ws_size,
                              hipStream_t stream) {
  const float* x  = (const float*)d_in[0];
  const float* Wq = (const float*)d_in[1];
  const float* Wk = (const float*)d_in[2];
  const float* Ww = (const float*)d_in[3];
  float* out = (float*)d_out;

  char* ws = (char*)d_ws;
  unsigned short* xb = (unsigned short*)ws;                 // 8192x2048 bf16 = 33,554,432 B
  unsigned short* Wp = (unsigned short*)(ws + 33554432);    // 640x2048 bf16  =  2,621,440 B
  unsigned short* qh = (unsigned short*)(ws + 36175872);    // 16x8192x32 bf16 = 8,388,608 B
  unsigned short* kh = (unsigned short*)(ws + 44564480);    // 8192x32 bf16   =    524,288 B
  float*          wf = (float*)(ws + 45088768);             // 8192x16 fp32   =    524,288 B

  pack_kernel<<<17664, 256, 0, stream>>>(x, Wq, Wk, Ww, xb, Wp);
  gemm_proj<<<dim3(5, 256), 256, 0, stream>>>(xb, Wp, qh, kh, wf);
  scores_kernel<<<dim3(32, 32, 2), 256, 0, stream>>>(qh, kh, wf, out);
}

// Round 8
// 291.721 us; speedup vs baseline: 1.0073x; 1.0073x over previous
//
#include <hip/hip_runtime.h>
#include <hip/hip_bf16.h>
#include <stdint.h>

// LightningIndexer: importance[b,q,k] = sum_h w[b,q,h] * relu( qh[b,q,:] . kv[b,k,:] )
// B=2, T=4096, C=2048, H=16, D=32.
// Pipeline: (1) cast x + pack W -> bf16, (2) MFMA GEMM projections (64x128 tiles,
// BK=64, T3-minimum single-barrier double-buffered LDS), (3) fused score kernel.
// Intermediates are HEAD-MAJOR (qh[16][8192][32], kh[8192][32]) so scores'
// fragment loads are direct, perfectly-coalesced 1KiB-per-wave global reads.

typedef __attribute__((ext_vector_type(8))) short bf16x8;
typedef __attribute__((ext_vector_type(4))) float f32x4;
typedef __attribute__((ext_vector_type(2))) __fp16 f16x2;   // clang builtin half2 type

__device__ __forceinline__ unsigned short f2bf(float f) {
  union { float f; unsigned u; } c; c.f = f;
  unsigned u = c.u;
  u += 0x7FFFu + ((u >> 16) & 1u);   // round-to-nearest-even
  return (unsigned short)(u >> 16);
}

__device__ __forceinline__ f16x2 u32_to_h2(unsigned u) {
  union { unsigned u; f16x2 h; } c; c.u = u; return c.h;
}
__device__ __forceinline__ unsigned h2_to_u32(f16x2 h) {
  union { unsigned u; f16x2 h; } c; c.h = h; return c.u;
}

__device__ __forceinline__ void async_copy16(void* lds, const void* g) {
  __builtin_amdgcn_global_load_lds(
      (const __attribute__((address_space(1))) unsigned*)g,
      (__attribute__((address_space(3))) unsigned*)lds, 16, 0, 0);
}

// ---------------- kernel 1: cast x to bf16, pack Wq/Wk/Ww (+zero pad) ----------------
__global__ __launch_bounds__(256) void pack_kernel(
    const float* __restrict__ x, const float* __restrict__ Wq,
    const float* __restrict__ Wk, const float* __restrict__ Ww,
    unsigned short* __restrict__ xb, unsigned short* __restrict__ Wp) {
  const int64_t NX4 = 16777216 / 4;          // x float4 count
  int64_t i = (int64_t)blockIdx.x * 256 + threadIdx.x;
  if (i < NX4) {
    float4 v = ((const float4*)x)[i];
    ushort4 o;
    o.x = f2bf(v.x); o.y = f2bf(v.y); o.z = f2bf(v.z); o.w = f2bf(v.w);
    ((ushort4*)xb)[i] = o;
  } else {
    int p = (int)(i - NX4);                  // 0 .. 640*2048/4-1 = 327679
    int row = p >> 9;                        // 512 float4 per 2048-col row
    int col = (p & 511) << 2;
    float4 v = make_float4(0.f, 0.f, 0.f, 0.f);
    if (row < 512)      v = *(const float4*)(Wq + (int64_t)row * 2048 + col);
    else if (row < 544) v = *(const float4*)(Wk + (int64_t)(row - 512) * 2048 + col);
    else if (row < 560) v = *(const float4*)(Ww + (int64_t)(row - 544) * 2048 + col);
    ushort4 o;
    o.x = f2bf(v.x); o.y = f2bf(v.y); o.z = f2bf(v.z); o.w = f2bf(v.w);
    ((ushort4*)Wp)[p] = o;
  }
}

// ---------------- kernel 2: projections, 64x128 tiles, BK=64, T3-minimum dbuf ----------------
// grid (5, 128): n-tile 128 (640 cols), m-tile 64 (8192 rows). 256 threads,
// waves 1x4 in n. Double-buffered LDS, ONE barrier per k-step, 32 k-steps:
//   prologue STAGE(buf0); barrier;
//   loop { STAGE(nxt) issued first; ds_read(cur); MFMA; barrier; }
// The barrier's vmcnt(0)+lgkmcnt(0) drain publishes nxt and protects cur.
__global__ __launch_bounds__(256) void gemm_proj(
    const unsigned short* __restrict__ xb, const unsigned short* __restrict__ Wp,
    unsigned short* __restrict__ qh, unsigned short* __restrict__ kh,
    float* __restrict__ wf) {
  __shared__ short lds_a[2][64 * 64];        // 2 x 8 KB
  __shared__ short lds_b[2][128 * 64];       // 2 x 16 KB
  const int tid = threadIdx.x;
  const int lane = tid & 63;
  const int l15 = lane & 15, quad = lane >> 4;
  const int wave = tid >> 6;
  const int wn = wave;                       // 0..3
  const int m0 = blockIdx.y * 64, n0 = blockIdx.x * 128;

  f32x4 acc[4][2] = {};

  // staging: A 64x64 = 512 chunks (2/thread), B 128x64 = 1024 chunks (4/thread)
  // chunk c: row = c>>3, slot = c&7 (8 x 16B chunks per 64-elem row)
#define STAGE_A(buf, ko)                                                        \
  {                                                                             \
    _Pragma("unroll") for (int cc = 0; cc < 2; ++cc) {                          \
      int c = tid + cc * 256;                                                   \
      async_copy16(&lds_a[buf][c * 8],                                          \
                   xb + (int64_t)(m0 + (c >> 3)) * 2048 + (ko) + (c & 7) * 8);  \
    }                                                                           \
  }
#define STAGE_B(buf, ko)                                                        \
  {                                                                             \
    _Pragma("unroll") for (int cc = 0; cc < 4; ++cc) {                          \
      int c = tid + cc * 256;                                                   \
      async_copy16(&lds_b[buf][c * 8],                                          \
                   Wp + (int64_t)(n0 + (c >> 3)) * 2048 + (ko) + (c & 7) * 8);  \
    }                                                                           \
  }

  STAGE_A(0, 0);
  STAGE_B(0, 0);
  __syncthreads();

  for (int kt = 0; kt < 32; ++kt) {
    const int cur = kt & 1, nxt = cur ^ 1;
    if (kt < 31) {                           // issue next-tile loads FIRST
      STAGE_A(nxt, (kt + 1) * 64);
      STAGE_B(nxt, (kt + 1) * 64);
    }
    bf16x8 af[4][2], bfr[2][2];
#pragma unroll
    for (int i = 0; i < 4; ++i)
#pragma unroll
      for (int s = 0; s < 2; ++s)
        af[i][s] = *(const bf16x8*)&lds_a[cur][(i * 16 + l15) * 64 + s * 32 + quad * 8];
#pragma unroll
    for (int j = 0; j < 2; ++j)
#pragma unroll
      for (int s = 0; s < 2; ++s)
        bfr[j][s] = *(const bf16x8*)&lds_b[cur][(wn * 32 + j * 16 + l15) * 64 + s * 32 + quad * 8];
#pragma unroll
    for (int s = 0; s < 2; ++s)
#pragma unroll
      for (int i = 0; i < 4; ++i)
#pragma unroll
        for (int j = 0; j < 2; ++j)
          acc[i][j] = __builtin_amdgcn_mfma_f32_16x16x32_bf16(af[i][s], bfr[j][s], acc[i][j], 0, 0, 0);
    __syncthreads();                         // publishes nxt, protects cur
  }
#undef STAGE_A
#undef STAGE_B

#pragma unroll
  for (int i = 0; i < 4; ++i)
#pragma unroll
    for (int j = 0; j < 2; ++j)
#pragma unroll
      for (int r = 0; r < 4; ++r) {
        int m = m0 + i * 16 + quad * 4 + r;
        int n = n0 + wn * 32 + j * 16 + l15;
        float v = acc[i][j][r];
        if (n < 512)      qh[((int64_t)(n >> 5) * 8192 + m) * 32 + (n & 31)] = f2bf(v);
        else if (n < 544) kh[(int64_t)m * 32 + (n - 512)] = f2bf(v);
        else if (n < 560) wf[m * 16 + (n - 544)] = v;   // w kept fp32
      }
}

// ---------------- kernel 3: fused scores ----------------
// Block: 128 k x 128 q tile (verified round-6 structure, unchanged). Fragment
// loads go directly to head-major qh/kh: within a wave, (l15, quad) lanes cover
// one contiguous 1 KiB block -> perfectly coalesced.
// Epilogue: cvt_pkrtz + pk_max + fdot2 = 1.5 VALU ops per element-head.
__global__ __launch_bounds__(256) void scores_kernel(
    const unsigned short* __restrict__ qh, const unsigned short* __restrict__ kh,
    const float* __restrict__ wf, float* __restrict__ out) {
  const int kt = blockIdx.x, qt = blockIdx.y, b = blockIdx.z;
  const int tid = threadIdx.x;
  const int lane = tid & 63;
  const int l15 = lane & 15, quad = lane >> 4;
  const int wave = tid >> 6;
  const int wk = wave & 1, wq = wave >> 1;

  __shared__ unsigned w2[8][132];            // packed half2 {w[q,2hp], w[q,2hp+1]}

  const int qrow0 = b * 4096 + qt * 128;
  const int krow0 = b * 4096 + kt * 128;

  // stage w tile: 128 rows x 16 heads fp32 -> half2 pairs (contiguous reads)
  {
    const float4* ws = (const float4*)(wf + (int64_t)qrow0 * 16);
#pragma unroll
    for (int r = 0; r < 2; ++r) {
      int f = tid * 2 + r;                   // 0..511 float4s
      float4 v = ws[f];
      int row = f >> 2, hb = (f & 3) * 4;    // heads hb..hb+3
      f16x2 p01, p23;
      p01.x = (__fp16)v.x; p01.y = (__fp16)v.y;
      p23.x = (__fp16)v.z; p23.y = (__fp16)v.w;
      w2[(hb >> 1) + 0][row] = h2_to_u32(p01);
      w2[(hb >> 1) + 1][row] = h2_to_u32(p23);
    }
  }

  // K fragments: shared across all heads, registers for whole kernel.
  bf16x8 ka[4];
#pragma unroll
  for (int i = 0; i < 4; ++i) {
    int kk = krow0 + wk * 64 + i * 16 + l15;
    ka[i] = *(const bf16x8*)&kh[(int64_t)kk * 32 + quad * 8];
  }

  // q base for this thread: head h, row offset j*16 -> + h*8192*32 + j*512
  const unsigned short* qbase =
      qh + (int64_t)(qrow0 + wq * 64 + l15) * 32 + quad * 8;

  f32x4 acc[4][4] = {};
  __syncthreads();

  const f16x2 hz = u32_to_h2(0u);
  const f32x4 z = {0.f, 0.f, 0.f, 0.f};

#pragma unroll
  for (int hp = 0; hp < 8; ++hp) {
    // loop-local q fragments (static indices only — no cross-iteration arrays)
    bf16x8 q0[4], q1[4];
#pragma unroll
    for (int j = 0; j < 4; ++j) {
      q0[j] = *(const bf16x8*)&qbase[(int64_t)(2 * hp) * 262144 + j * 512];
      q1[j] = *(const bf16x8*)&qbase[(int64_t)(2 * hp + 1) * 262144 + j * 512];
    }
    f16x2 wv[4];
#pragma unroll
    for (int j = 0; j < 4; ++j)
      wv[j] = u32_to_h2(w2[hp][wq * 64 + j * 16 + l15]);

#pragma unroll
    for (int i = 0; i < 4; ++i)
#pragma unroll
      for (int j = 0; j < 4; ++j) {
        f32x4 t0 = __builtin_amdgcn_mfma_f32_16x16x32_bf16(ka[i], q0[j], z, 0, 0, 0);
        f32x4 t1 = __builtin_amdgcn_mfma_f32_16x16x32_bf16(ka[i], q1[j], z, 0, 0, 0);
#pragma unroll
        for (int r = 0; r < 4; ++r) {
          f16x2 p = __builtin_amdgcn_cvt_pkrtz(t0[r], t1[r]);   // {s_h0, s_h1} f16
          p = __builtin_elementwise_max(p, hz);                  // relu both halves
          acc[i][j][r] = __builtin_amdgcn_fdot2(p, wv[j], acc[i][j][r], false);
        }
      }
  }

  // store: per (i,j) one dwordx4 along k
#pragma unroll
  for (int i = 0; i < 4; ++i)
#pragma unroll
    for (int j = 0; j < 4; ++j) {
      int q = qt * 128 + wq * 64 + j * 16 + l15;
      int k = kt * 128 + wk * 64 + i * 16 + quad * 4;
      float4 v = make_float4(acc[i][j][0], acc[i][j][1], acc[i][j][2], acc[i][j][3]);
      *(float4*)&out[((int64_t)b * 4096 + q) * 4096 + k] = v;
    }
}

extern "C" void kernel_launch(void* const* d_in, const int* in_sizes, int n_in,
                              void* d_out, int out_size, void* d_ws, size_t ws_size,
                              hipStream_t stream) {
  const float* x  = (const float*)d_in[0];
  const float* Wq = (const float*)d_in[1];
  const float* Wk = (const float*)d_in[2];
  const float* Ww = (const float*)d_in[3];
  float* out = (float*)d_out;

  char* ws = (char*)d_ws;
  unsigned short* xb = (unsigned short*)ws;                 // 8192x2048 bf16 = 33,554,432 B
  unsigned short* Wp = (unsigned short*)(ws + 33554432);    // 640x2048 bf16  =  2,621,440 B
  unsigned short* qh = (unsigned short*)(ws + 36175872);    // 16x8192x32 bf16 = 8,388,608 B
  unsigned short* kh = (unsigned short*)(ws + 44564480);    // 8192x32 bf16   =    524,288 B
  float*          wf = (float*)(ws + 45088768);             // 8192x16 fp32   =    524,288 B

  pack_kernel<<<17664, 256, 0, stream>>>(x, Wq, Wk, Ww, xb, Wp);
  gemm_proj<<<dim3(5, 128), 256, 0, stream>>>(xb, Wp, qh, kh, wf);
  scores_kernel<<<dim3(32, 32, 2), 256, 0, stream>>>(qh, kh, wf, out);
}

// Round 9
// 287.129 us; speedup vs baseline: 1.0234x; 1.0160x over previous
//
#include <hip/hip_runtime.h>
#include <hip/hip_bf16.h>
#include <stdint.h>

// LightningIndexer: importance[b,q,k] = sum_h w[b,q,h] * relu( qh[b,q,:] . kv[b,k,:] )
// B=2, T=4096, C=2048, H=16, D=32.
// Pipeline: (1) pack W -> bf16 (tiny), (2) MFMA GEMM projections reading x f32
// DIRECTLY (fused cast in A-staging: global->reg->cvt->LDS, T14 split), with
// B via global_load_lds; 64x128 tiles, BK=64, T3 single-barrier dbuf.
// (3) fused score kernel (verified round-6 structure, unchanged).
// Intermediates HEAD-MAJOR (qh[16][8192][32], kh[8192][32]) -> coalesced loads.

typedef __attribute__((ext_vector_type(8))) short bf16x8;
typedef __attribute__((ext_vector_type(4))) float f32x4;
typedef __attribute__((ext_vector_type(2))) __fp16 f16x2;   // clang builtin half2 type

__device__ __forceinline__ unsigned short f2bf(float f) {
  union { float f; unsigned u; } c; c.f = f;
  unsigned u = c.u;
  u += 0x7FFFu + ((u >> 16) & 1u);   // round-to-nearest-even
  return (unsigned short)(u >> 16);
}

__device__ __forceinline__ f16x2 u32_to_h2(unsigned u) {
  union { unsigned u; f16x2 h; } c; c.u = u; return c.h;
}
__device__ __forceinline__ unsigned h2_to_u32(f16x2 h) {
  union { unsigned u; f16x2 h; } c; c.h = h; return c.u;
}

__device__ __forceinline__ void async_copy16(void* lds, const void* g) {
  __builtin_amdgcn_global_load_lds(
      (const __attribute__((address_space(1))) unsigned*)g,
      (__attribute__((address_space(3))) unsigned*)lds, 16, 0, 0);
}

// ---------------- kernel 1: pack Wq/Wk/Ww -> bf16 (+zero pad). 1280 blocks. ----------------
__global__ __launch_bounds__(256) void packw_kernel(
    const float* __restrict__ Wq, const float* __restrict__ Wk,
    const float* __restrict__ Ww, unsigned short* __restrict__ Wp) {
  int p = blockIdx.x * 256 + threadIdx.x;    // 0 .. 640*2048/4-1 = 327679
  int row = p >> 9;                          // 512 float4 per 2048-col row
  int col = (p & 511) << 2;
  float4 v = make_float4(0.f, 0.f, 0.f, 0.f);
  if (row < 512)      v = *(const float4*)(Wq + (int64_t)row * 2048 + col);
  else if (row < 544) v = *(const float4*)(Wk + (int64_t)(row - 512) * 2048 + col);
  else if (row < 560) v = *(const float4*)(Ww + (int64_t)(row - 544) * 2048 + col);
  ushort4 o;
  o.x = f2bf(v.x); o.y = f2bf(v.y); o.z = f2bf(v.z); o.w = f2bf(v.w);
  ((ushort4*)Wp)[p] = o;
}

// ---------------- kernel 2: projections, 64x128 tiles, BK=64, fused x-cast ----------------
// grid (5, 128): n-tile 128 (640 cols), m-tile 64 (8192 rows). 256 threads,
// waves 1x4 in n. Double-buffered LDS, ONE barrier per k-step, 32 k-steps:
//   loop { issue A f32 loads (regs, for nxt); B global_load_lds(nxt);
//          ds_read(cur); MFMA; cvt+ds_write A->nxt; barrier; }
// A-stage per thread: row = tid>>2, cols (tid&3)*16..+15 = 4x float4 -> 16 bf16.
__global__ __launch_bounds__(256) void gemm_proj(
    const float* __restrict__ x, const unsigned short* __restrict__ Wp,
    unsigned short* __restrict__ qh, unsigned short* __restrict__ kh,
    float* __restrict__ wf) {
  __shared__ short lds_a[2][64 * 64];        // 2 x 8 KB
  __shared__ short lds_b[2][128 * 64];       // 2 x 16 KB
  const int tid = threadIdx.x;
  const int lane = tid & 63;
  const int l15 = lane & 15, quad = lane >> 4;
  const int wave = tid >> 6;
  const int wn = wave;                       // 0..3
  const int m0 = blockIdx.y * 64, n0 = blockIdx.x * 128;

  const int arow = tid >> 2, acg = tid & 3;  // A stage coords
  const float* gax = x + (int64_t)(m0 + arow) * 2048 + acg * 16;
  short* lda_dst0 = &lds_a[0][arow * 64 + acg * 16];
  short* lda_dst1 = &lds_a[1][arow * 64 + acg * 16];

  f32x4 acc[4][2] = {};

#define STAGE_B(buf, ko)                                                        \
  {                                                                             \
    _Pragma("unroll") for (int cc = 0; cc < 4; ++cc) {                          \
      int c = tid + cc * 256;                                                   \
      async_copy16(&lds_b[buf][c * 8],                                          \
                   Wp + (int64_t)(n0 + (c >> 3)) * 2048 + (ko) + (c & 7) * 8);  \
    }                                                                           \
  }
#define LOAD_A(ko)                                                              \
  f32x4 av0 = *(const f32x4*)(gax + (ko));                                      \
  f32x4 av1 = *(const f32x4*)(gax + (ko) + 4);                                  \
  f32x4 av2 = *(const f32x4*)(gax + (ko) + 8);                                  \
  f32x4 av3 = *(const f32x4*)(gax + (ko) + 12);
#define WRITE_A(dst)                                                            \
  {                                                                             \
    bf16x8 w0, w1;                                                              \
    w0[0] = (short)f2bf(av0[0]); w0[1] = (short)f2bf(av0[1]);                   \
    w0[2] = (short)f2bf(av0[2]); w0[3] = (short)f2bf(av0[3]);                   \
    w0[4] = (short)f2bf(av1[0]); w0[5] = (short)f2bf(av1[1]);                   \
    w0[6] = (short)f2bf(av1[2]); w0[7] = (short)f2bf(av1[3]);                   \
    w1[0] = (short)f2bf(av2[0]); w1[1] = (short)f2bf(av2[1]);                   \
    w1[2] = (short)f2bf(av2[2]); w1[3] = (short)f2bf(av2[3]);                   \
    w1[4] = (short)f2bf(av3[0]); w1[5] = (short)f2bf(av3[1]);                   \
    w1[6] = (short)f2bf(av3[2]); w1[7] = (short)f2bf(av3[3]);                   \
    *(bf16x8*)(dst) = w0;                                                       \
    *(bf16x8*)((dst) + 8) = w1;                                                 \
  }

  // prologue: stage k-step 0 into buf 0
  {
    LOAD_A(0);
    STAGE_B(0, 0);
    WRITE_A(lda_dst0);
  }
  __syncthreads();

  for (int kt = 0; kt < 32; ++kt) {
    const int cur = kt & 1;
    // issue next A loads first (latency hides under MFMA below)
    f32x4 av0, av1, av2, av3;
    if (kt < 31) {
      const float* g = gax + (kt + 1) * 64;
      av0 = *(const f32x4*)(g);
      av1 = *(const f32x4*)(g + 4);
      av2 = *(const f32x4*)(g + 8);
      av3 = *(const f32x4*)(g + 12);
      STAGE_B(cur ^ 1, (kt + 1) * 64);
    }
    bf16x8 af[4][2], bfr[2][2];
#pragma unroll
    for (int i = 0; i < 4; ++i)
#pragma unroll
      for (int s = 0; s < 2; ++s)
        af[i][s] = *(const bf16x8*)&lds_a[cur][(i * 16 + l15) * 64 + s * 32 + quad * 8];
#pragma unroll
    for (int j = 0; j < 2; ++j)
#pragma unroll
      for (int s = 0; s < 2; ++s)
        bfr[j][s] = *(const bf16x8*)&lds_b[cur][(wn * 32 + j * 16 + l15) * 64 + s * 32 + quad * 8];
#pragma unroll
    for (int s = 0; s < 2; ++s)
#pragma unroll
      for (int i = 0; i < 4; ++i)
#pragma unroll
        for (int j = 0; j < 2; ++j)
          acc[i][j] = __builtin_amdgcn_mfma_f32_16x16x32_bf16(af[i][s], bfr[j][s], acc[i][j], 0, 0, 0);
    if (kt < 31) {                           // write-late: cvt + ds_write into nxt
      short* dst = (cur ^ 1) ? lda_dst1 : lda_dst0;
      WRITE_A(dst);
    }
    __syncthreads();                         // publishes nxt (A writes + B loads), protects cur
  }
#undef STAGE_B
#undef LOAD_A
#undef WRITE_A

#pragma unroll
  for (int i = 0; i < 4; ++i)
#pragma unroll
    for (int j = 0; j < 2; ++j)
#pragma unroll
      for (int r = 0; r < 4; ++r) {
        int m = m0 + i * 16 + quad * 4 + r;
        int n = n0 + wn * 32 + j * 16 + l15;
        float v = acc[i][j][r];
        if (n < 512)      qh[((int64_t)(n >> 5) * 8192 + m) * 32 + (n & 31)] = f2bf(v);
        else if (n < 544) kh[(int64_t)m * 32 + (n - 512)] = f2bf(v);
        else if (n < 560) wf[m * 16 + (n - 544)] = v;   // w kept fp32
      }
}

// ---------------- kernel 3: fused scores ----------------
// Block: 128 k x 128 q tile (verified round-6 structure, unchanged). Fragment
// loads go directly to head-major qh/kh: within a wave, (l15, quad) lanes cover
// one contiguous 1 KiB block -> perfectly coalesced.
// Epilogue: cvt_pkrtz + pk_max + fdot2 = 1.5 VALU ops per element-head.
__global__ __launch_bounds__(256) void scores_kernel(
    const unsigned short* __restrict__ qh, const unsigned short* __restrict__ kh,
    const float* __restrict__ wf, float* __restrict__ out) {
  const int kt = blockIdx.x, qt = blockIdx.y, b = blockIdx.z;
  const int tid = threadIdx.x;
  const int lane = tid & 63;
  const int l15 = lane & 15, quad = lane >> 4;
  const int wave = tid >> 6;
  const int wk = wave & 1, wq = wave >> 1;

  __shared__ unsigned w2[8][132];            // packed half2 {w[q,2hp], w[q,2hp+1]}

  const int qrow0 = b * 4096 + qt * 128;
  const int krow0 = b * 4096 + kt * 128;

  // stage w tile: 128 rows x 16 heads fp32 -> half2 pairs (contiguous reads)
  {
    const float4* ws = (const float4*)(wf + (int64_t)qrow0 * 16);
#pragma unroll
    for (int r = 0; r < 2; ++r) {
      int f = tid * 2 + r;                   // 0..511 float4s
      float4 v = ws[f];
      int row = f >> 2, hb = (f & 3) * 4;    // heads hb..hb+3
      f16x2 p01, p23;
      p01.x = (__fp16)v.x; p01.y = (__fp16)v.y;
      p23.x = (__fp16)v.z; p23.y = (__fp16)v.w;
      w2[(hb >> 1) + 0][row] = h2_to_u32(p01);
      w2[(hb >> 1) + 1][row] = h2_to_u32(p23);
    }
  }

  // K fragments: shared across all heads, registers for whole kernel.
  bf16x8 ka[4];
#pragma unroll
  for (int i = 0; i < 4; ++i) {
    int kk = krow0 + wk * 64 + i * 16 + l15;
    ka[i] = *(const bf16x8*)&kh[(int64_t)kk * 32 + quad * 8];
  }

  // q base for this thread: head h, row offset j*16 -> + h*8192*32 + j*512
  const unsigned short* qbase =
      qh + (int64_t)(qrow0 + wq * 64 + l15) * 32 + quad * 8;

  f32x4 acc[4][4] = {};
  __syncthreads();

  const f16x2 hz = u32_to_h2(0u);
  const f32x4 z = {0.f, 0.f, 0.f, 0.f};

#pragma unroll
  for (int hp = 0; hp < 8; ++hp) {
    // loop-local q fragments (static indices only — no cross-iteration arrays)
    bf16x8 q0[4], q1[4];
#pragma unroll
    for (int j = 0; j < 4; ++j) {
      q0[j] = *(const bf16x8*)&qbase[(int64_t)(2 * hp) * 262144 + j * 512];
      q1[j] = *(const bf16x8*)&qbase[(int64_t)(2 * hp + 1) * 262144 + j * 512];
    }
    f16x2 wv[4];
#pragma unroll
    for (int j = 0; j < 4; ++j)
      wv[j] = u32_to_h2(w2[hp][wq * 64 + j * 16 + l15]);

#pragma unroll
    for (int i = 0; i < 4; ++i)
#pragma unroll
      for (int j = 0; j < 4; ++j) {
        f32x4 t0 = __builtin_amdgcn_mfma_f32_16x16x32_bf16(ka[i], q0[j], z, 0, 0, 0);
        f32x4 t1 = __builtin_amdgcn_mfma_f32_16x16x32_bf16(ka[i], q1[j], z, 0, 0, 0);
#pragma unroll
        for (int r = 0; r < 4; ++r) {
          f16x2 p = __builtin_amdgcn_cvt_pkrtz(t0[r], t1[r]);   // {s_h0, s_h1} f16
          p = __builtin_elementwise_max(p, hz);                  // relu both halves
          acc[i][j][r] = __builtin_amdgcn_fdot2(p, wv[j], acc[i][j][r], false);
        }
      }
  }

  // store: per (i,j) one dwordx4 along k
#pragma unroll
  for (int i = 0; i < 4; ++i)
#pragma unroll
    for (int j = 0; j < 4; ++j) {
      int q = qt * 128 + wq * 64 + j * 16 + l15;
      int k = kt * 128 + wk * 64 + i * 16 + quad * 4;
      float4 v = make_float4(acc[i][j][0], acc[i][j][1], acc[i][j][2], acc[i][j][3]);
      *(float4*)&out[((int64_t)b * 4096 + q) * 4096 + k] = v;
    }
}

extern "C" void kernel_launch(void* const* d_in, const int* in_sizes, int n_in,
                              void* d_out, int out_size, void* d_ws, size_t ws_size,
                              hipStream_t stream) {
  const float* x  = (const float*)d_in[0];
  const float* Wq = (const float*)d_in[1];
  const float* Wk = (const float*)d_in[2];
  const float* Ww = (const float*)d_in[3];
  float* out = (float*)d_out;

  char* ws = (char*)d_ws;
  unsigned short* Wp = (unsigned short*)ws;                 // 640x2048 bf16  =  2,621,440 B
  unsigned short* qh = (unsigned short*)(ws + 2621440);     // 16x8192x32 bf16 = 8,388,608 B
  unsigned short* kh = (unsigned short*)(ws + 11010048);    // 8192x32 bf16   =    524,288 B
  float*          wf = (float*)(ws + 11534336);             // 8192x16 fp32   =    524,288 B

  packw_kernel<<<1280, 256, 0, stream>>>(Wq, Wk, Ww, Wp);
  gemm_proj<<<dim3(5, 128), 256, 0, stream>>>(x, Wp, qh, kh, wf);
  scores_kernel<<<dim3(32, 32, 2), 256, 0, stream>>>(qh, kh, wf, out);
}

// Round 10
// 282.730 us; speedup vs baseline: 1.0393x; 1.0156x over previous
//
#include <hip/hip_runtime.h>
#include <hip/hip_bf16.h>
#include <stdint.h>

// LightningIndexer: importance[b,q,k] = sum_h w[b,q,h] * relu( qh[b,q,:] . kv[b,k,:] )
// B=2, T=4096, C=2048, H=16, D=32.
// Pipeline: (1) pack W -> bf16 (tiny), (2) MFMA GEMM projections reading x f32
// directly (fused cast in A-staging), 64x128 tiles, BK=64, T3 single-barrier dbuf,
// T2 16B-chunk XOR swizzle (both-sides) + XCD-bijective block swizzle.
// (3) fused score kernel (verified round-6 structure, unchanged).
// Intermediates HEAD-MAJOR (qh[16][8192][32], kh[8192][32]) -> coalesced loads.

typedef __attribute__((ext_vector_type(8))) short bf16x8;
typedef __attribute__((ext_vector_type(4))) float f32x4;
typedef __attribute__((ext_vector_type(2))) __fp16 f16x2;   // clang builtin half2 type

__device__ __forceinline__ unsigned short f2bf(float f) {
  union { float f; unsigned u; } c; c.f = f;
  unsigned u = c.u;
  u += 0x7FFFu + ((u >> 16) & 1u);   // round-to-nearest-even
  return (unsigned short)(u >> 16);
}

__device__ __forceinline__ f16x2 u32_to_h2(unsigned u) {
  union { unsigned u; f16x2 h; } c; c.u = u; return c.h;
}
__device__ __forceinline__ unsigned h2_to_u32(f16x2 h) {
  union { unsigned u; f16x2 h; } c; c.h = h; return c.u;
}

__device__ __forceinline__ void async_copy16(void* lds, const void* g) {
  __builtin_amdgcn_global_load_lds(
      (const __attribute__((address_space(1))) unsigned*)g,
      (__attribute__((address_space(3))) unsigned*)lds, 16, 0, 0);
}

// ---------------- kernel 1: pack Wq/Wk/Ww -> bf16 (+zero pad). 1280 blocks. ----------------
__global__ __launch_bounds__(256) void packw_kernel(
    const float* __restrict__ Wq, const float* __restrict__ Wk,
    const float* __restrict__ Ww, unsigned short* __restrict__ Wp) {
  int p = blockIdx.x * 256 + threadIdx.x;    // 0 .. 640*2048/4-1 = 327679
  int row = p >> 9;                          // 512 float4 per 2048-col row
  int col = (p & 511) << 2;
  float4 v = make_float4(0.f, 0.f, 0.f, 0.f);
  if (row < 512)      v = *(const float4*)(Wq + (int64_t)row * 2048 + col);
  else if (row < 544) v = *(const float4*)(Wk + (int64_t)(row - 512) * 2048 + col);
  else if (row < 560) v = *(const float4*)(Ww + (int64_t)(row - 544) * 2048 + col);
  ushort4 o;
  o.x = f2bf(v.x); o.y = f2bf(v.y); o.z = f2bf(v.z); o.w = f2bf(v.w);
  ((ushort4*)Wp)[p] = o;
}

// ---------------- kernel 2: projections, 64x128 tiles, BK=64, fused x-cast ----------------
// grid (5, 128) -> flat L, XCD-bijective remap L' = (L&7)*80 + (L>>3) so the 5
// n-tiles sharing an A-panel land on ONE XCD's L2 (640%8==0 -> bijective).
// LDS tiles are [row][8 x 16B chunks]; chunk slot s of row r holds global chunk
// s^(r&7) (T2 swizzle, both sides): B pre-swizzles the global_load_lds SOURCE
// (LDS dest linear, as HW requires); A swizzles its ds_write slots; all reads
// use slot = cg ^ (r&7). Per-instruction bank-set occupancy becomes uniform.
__global__ __launch_bounds__(256) void gemm_proj(
    const float* __restrict__ x, const unsigned short* __restrict__ Wp,
    unsigned short* __restrict__ qh, unsigned short* __restrict__ kh,
    float* __restrict__ wf) {
  __shared__ short lds_a[2][64 * 64];        // 2 x 8 KB
  __shared__ short lds_b[2][128 * 64];       // 2 x 16 KB
  const int tid = threadIdx.x;
  const int lane = tid & 63;
  const int l15 = lane & 15, quad = lane >> 4;
  const int wave = tid >> 6;
  const int wn = wave;                       // 0..3
  const int L = blockIdx.x + 5 * blockIdx.y; // hw dispatch order (x fastest)
  const int Lp = (L & 7) * 80 + (L >> 3);    // XCD-contiguous chunks of 80
  const int m0 = (Lp / 5) * 64, n0 = (Lp % 5) * 128;

  const int arow = tid >> 2, acg = tid & 3;  // A stage coords (16 f32 / thread)
  const float* gax = x + (int64_t)(m0 + arow) * 2048 + acg * 16;
  // swizzled A write slots (two 16B chunks: 2*acg, 2*acg+1)
  const int as0 = ((acg * 2)     ^ (arow & 7)) * 8;
  const int as1 = ((acg * 2 + 1) ^ (arow & 7)) * 8;
  short* lda_d0[2] = { &lds_a[0][arow * 64 + as0], &lds_a[1][arow * 64 + as0] };
  short* lda_d1[2] = { &lds_a[0][arow * 64 + as1], &lds_a[1][arow * 64 + as1] };

  f32x4 acc[4][2] = {};

#define STAGE_B(buf, ko)                                                        \
  {                                                                             \
    _Pragma("unroll") for (int cc = 0; cc < 4; ++cc) {                          \
      int c = tid + cc * 256;                                                   \
      int br = c >> 3, bs = (c & 7) ^ (br & 7);                                 \
      async_copy16(&lds_b[buf][c * 8],                                          \
                   Wp + (int64_t)(n0 + br) * 2048 + (ko) + bs * 8);             \
    }                                                                           \
  }
#define WRITE_A(d0, d1)                                                         \
  {                                                                             \
    bf16x8 w0, w1;                                                              \
    w0[0] = (short)f2bf(av0[0]); w0[1] = (short)f2bf(av0[1]);                   \
    w0[2] = (short)f2bf(av0[2]); w0[3] = (short)f2bf(av0[3]);                   \
    w0[4] = (short)f2bf(av1[0]); w0[5] = (short)f2bf(av1[1]);                   \
    w0[6] = (short)f2bf(av1[2]); w0[7] = (short)f2bf(av1[3]);                   \
    w1[0] = (short)f2bf(av2[0]); w1[1] = (short)f2bf(av2[1]);                   \
    w1[2] = (short)f2bf(av2[2]); w1[3] = (short)f2bf(av2[3]);                   \
    w1[4] = (short)f2bf(av3[0]); w1[5] = (short)f2bf(av3[1]);                   \
    w1[6] = (short)f2bf(av3[2]); w1[7] = (short)f2bf(av3[3]);                   \
    *(bf16x8*)(d0) = w0;                                                        \
    *(bf16x8*)(d1) = w1;                                                        \
  }

  // prologue: stage k-step 0 into buf 0
  {
    f32x4 av0 = *(const f32x4*)(gax);
    f32x4 av1 = *(const f32x4*)(gax + 4);
    f32x4 av2 = *(const f32x4*)(gax + 8);
    f32x4 av3 = *(const f32x4*)(gax + 12);
    STAGE_B(0, 0);
    WRITE_A(lda_d0[0], lda_d1[0]);
  }
  __syncthreads();

  for (int kt = 0; kt < 32; ++kt) {
    const int cur = kt & 1;
    // issue next A loads first (latency hides under MFMA below)
    f32x4 av0, av1, av2, av3;
    if (kt < 31) {
      const float* g = gax + (kt + 1) * 64;
      av0 = *(const f32x4*)(g);
      av1 = *(const f32x4*)(g + 4);
      av2 = *(const f32x4*)(g + 8);
      av3 = *(const f32x4*)(g + 12);
      STAGE_B(cur ^ 1, (kt + 1) * 64);
    }
    bf16x8 af[4][2], bfr[2][2];
#pragma unroll
    for (int i = 0; i < 4; ++i)
#pragma unroll
      for (int s = 0; s < 2; ++s) {
        int r = i * 16 + l15, cg = s * 4 + quad;
        af[i][s] = *(const bf16x8*)&lds_a[cur][r * 64 + (cg ^ (r & 7)) * 8];
      }
#pragma unroll
    for (int j = 0; j < 2; ++j)
#pragma unroll
      for (int s = 0; s < 2; ++s) {
        int r = wn * 32 + j * 16 + l15, cg = s * 4 + quad;
        bfr[j][s] = *(const bf16x8*)&lds_b[cur][r * 64 + (cg ^ (r & 7)) * 8];
      }
#pragma unroll
    for (int s = 0; s < 2; ++s)
#pragma unroll
      for (int i = 0; i < 4; ++i)
#pragma unroll
        for (int j = 0; j < 2; ++j)
          acc[i][j] = __builtin_amdgcn_mfma_f32_16x16x32_bf16(af[i][s], bfr[j][s], acc[i][j], 0, 0, 0);
    if (kt < 31) {                           // write-late: cvt + ds_write into nxt
      WRITE_A(lda_d0[cur ^ 1], lda_d1[cur ^ 1]);
    }
    __syncthreads();                         // publishes nxt (A writes + B loads), protects cur
  }
#undef STAGE_B
#undef WRITE_A

#pragma unroll
  for (int i = 0; i < 4; ++i)
#pragma unroll
    for (int j = 0; j < 2; ++j)
#pragma unroll
      for (int r = 0; r < 4; ++r) {
        int m = m0 + i * 16 + quad * 4 + r;
        int n = n0 + wn * 32 + j * 16 + l15;
        float v = acc[i][j][r];
        if (n < 512)      qh[((int64_t)(n >> 5) * 8192 + m) * 32 + (n & 31)] = f2bf(v);
        else if (n < 544) kh[(int64_t)m * 32 + (n - 512)] = f2bf(v);
        else if (n < 560) wf[m * 16 + (n - 544)] = v;   // w kept fp32
      }
}

// ---------------- kernel 3: fused scores ----------------
// Block: 128 k x 128 q tile (verified round-6 structure, unchanged). Fragment
// loads go directly to head-major qh/kh: within a wave, (l15, quad) lanes cover
// one contiguous 1 KiB block -> perfectly coalesced.
// Epilogue: cvt_pkrtz + pk_max + fdot2 = 1.5 VALU ops per element-head.
__global__ __launch_bounds__(256) void scores_kernel(
    const unsigned short* __restrict__ qh, const unsigned short* __restrict__ kh,
    const float* __restrict__ wf, float* __restrict__ out) {
  const int kt = blockIdx.x, qt = blockIdx.y, b = blockIdx.z;
  const int tid = threadIdx.x;
  const int lane = tid & 63;
  const int l15 = lane & 15, quad = lane >> 4;
  const int wave = tid >> 6;
  const int wk = wave & 1, wq = wave >> 1;

  __shared__ unsigned w2[8][132];            // packed half2 {w[q,2hp], w[q,2hp+1]}

  const int qrow0 = b * 4096 + qt * 128;
  const int krow0 = b * 4096 + kt * 128;

  // stage w tile: 128 rows x 16 heads fp32 -> half2 pairs (contiguous reads)
  {
    const float4* ws = (const float4*)(wf + (int64_t)qrow0 * 16);
#pragma unroll
    for (int r = 0; r < 2; ++r) {
      int f = tid * 2 + r;                   // 0..511 float4s
      float4 v = ws[f];
      int row = f >> 2, hb = (f & 3) * 4;    // heads hb..hb+3
      f16x2 p01, p23;
      p01.x = (__fp16)v.x; p01.y = (__fp16)v.y;
      p23.x = (__fp16)v.z; p23.y = (__fp16)v.w;
      w2[(hb >> 1) + 0][row] = h2_to_u32(p01);
      w2[(hb >> 1) + 1][row] = h2_to_u32(p23);
    }
  }

  // K fragments: shared across all heads, registers for whole kernel.
  bf16x8 ka[4];
#pragma unroll
  for (int i = 0; i < 4; ++i) {
    int kk = krow0 + wk * 64 + i * 16 + l15;
    ka[i] = *(const bf16x8*)&kh[(int64_t)kk * 32 + quad * 8];
  }

  // q base for this thread: head h, row offset j*16 -> + h*8192*32 + j*512
  const unsigned short* qbase =
      qh + (int64_t)(qrow0 + wq * 64 + l15) * 32 + quad * 8;

  f32x4 acc[4][4] = {};
  __syncthreads();

  const f16x2 hz = u32_to_h2(0u);
  const f32x4 z = {0.f, 0.f, 0.f, 0.f};

#pragma unroll
  for (int hp = 0; hp < 8; ++hp) {
    // loop-local q fragments (static indices only — no cross-iteration arrays)
    bf16x8 q0[4], q1[4];
#pragma unroll
    for (int j = 0; j < 4; ++j) {
      q0[j] = *(const bf16x8*)&qbase[(int64_t)(2 * hp) * 262144 + j * 512];
      q1[j] = *(const bf16x8*)&qbase[(int64_t)(2 * hp + 1) * 262144 + j * 512];
    }
    f16x2 wv[4];
#pragma unroll
    for (int j = 0; j < 4; ++j)
      wv[j] = u32_to_h2(w2[hp][wq * 64 + j * 16 + l15]);

#pragma unroll
    for (int i = 0; i < 4; ++i)
#pragma unroll
      for (int j = 0; j < 4; ++j) {
        f32x4 t0 = __builtin_amdgcn_mfma_f32_16x16x32_bf16(ka[i], q0[j], z, 0, 0, 0);
        f32x4 t1 = __builtin_amdgcn_mfma_f32_16x16x32_bf16(ka[i], q1[j], z, 0, 0, 0);
#pragma unroll
        for (int r = 0; r < 4; ++r) {
          f16x2 p = __builtin_amdgcn_cvt_pkrtz(t0[r], t1[r]);   // {s_h0, s_h1} f16
          p = __builtin_elementwise_max(p, hz);                  // relu both halves
          acc[i][j][r] = __builtin_amdgcn_fdot2(p, wv[j], acc[i][j][r], false);
        }
      }
  }

  // store: per (i,j) one dwordx4 along k
#pragma unroll
  for (int i = 0; i < 4; ++i)
#pragma unroll
    for (int j = 0; j < 4; ++j) {
      int q = qt * 128 + wq * 64 + j * 16 + l15;
      int k = kt * 128 + wk * 64 + i * 16 + quad * 4;
      float4 v = make_float4(acc[i][j][0], acc[i][j][1], acc[i][j][2], acc[i][j][3]);
      *(float4*)&out[((int64_t)b * 4096 + q) * 4096 + k] = v;
    }
}

extern "C" void kernel_launch(void* const* d_in, const int* in_sizes, int n_in,
                              void* d_out, int out_size, void* d_ws, size_t ws_size,
                              hipStream_t stream) {
  const float* x  = (const float*)d_in[0];
  const float* Wq = (const float*)d_in[1];
  const float* Wk = (const float*)d_in[2];
  const float* Ww = (const float*)d_in[3];
  float* out = (float*)d_out;

  char* ws = (char*)d_ws;
  unsigned short* Wp = (unsigned short*)ws;                 // 640x2048 bf16  =  2,621,440 B
  unsigned short* qh = (unsigned short*)(ws + 2621440);     // 16x8192x32 bf16 = 8,388,608 B
  unsigned short* kh = (unsigned short*)(ws + 11010048);    // 8192x32 bf16   =    524,288 B
  float*          wf = (float*)(ws + 11534336);             // 8192x16 fp32   =    524,288 B

  packw_kernel<<<1280, 256, 0, stream>>>(Wq, Wk, Ww, Wp);
  gemm_proj<<<dim3(5, 128), 256, 0, stream>>>(x, Wp, qh, kh, wf);
  scores_kernel<<<dim3(32, 32, 2), 256, 0, stream>>>(qh, kh, wf, out);
}